// Round 3
// baseline (781.245 us; speedup 1.0000x reference)
//
#include <hip/hip_runtime.h>
#include <cmath>

#define NODES 40000
#define EDGES 600000
#define HD    128
#define BN_EPS 1e-5f

// ---------------- CSR build ----------------

__global__ __launch_bounds__(256) void zero_i(int* __restrict__ p, int n) {
  int i = blockIdx.x * 256 + threadIdx.x;
  if (i < n) p[i] = 0;
}

__global__ __launch_bounds__(256) void hist_dst(const int* __restrict__ ei,
                                                int* __restrict__ deg) {
  int e = blockIdx.x * 256 + threadIdx.x;
  if (e < EDGES) atomicAdd(&deg[ei[EDGES + e]], 1);
}

// exclusive scan of deg[NODES] -> off[NODES+1]; single block of 1024.
__global__ __launch_bounds__(1024) void exscan(const int* __restrict__ deg,
                                               int* __restrict__ off) {
  __shared__ int wsum[16];
  __shared__ int carry_s;
  const int tid = threadIdx.x;
  const int lane = tid & 63, wv = tid >> 6;
  if (tid == 0) carry_s = 0;
  __syncthreads();
  for (int base = 0; base < NODES; base += 1024) {
    int i = base + tid;
    int v = (i < NODES) ? deg[i] : 0;
    int s = v;
#pragma unroll
    for (int d = 1; d < 64; d <<= 1) {
      int t = __shfl_up(s, d, 64);
      if (lane >= d) s += t;
    }
    if (lane == 63) wsum[wv] = s;
    __syncthreads();
    if (wv == 0) {
      int ws = (lane < 16) ? wsum[lane] : 0;
#pragma unroll
      for (int d = 1; d < 16; d <<= 1) {
        int t = __shfl_up(ws, d, 64);
        if (lane >= d) ws += t;
      }
      if (lane < 16) wsum[lane] = ws;
    }
    __syncthreads();
    int carry = carry_s;
    int excl = carry + (wv > 0 ? wsum[wv - 1] : 0) + s - v;
    if (i < NODES) off[i] = excl;
    __syncthreads();
    if (tid == 1023) carry_s = carry + wsum[15];
    __syncthreads();
  }
  if (tid == 0) off[NODES] = carry_s;
}

__global__ __launch_bounds__(256) void copy_i(const int* __restrict__ a,
                                              int* __restrict__ b, int n) {
  int i = blockIdx.x * 256 + threadIdx.x;
  if (i < n) b[i] = a[i];
}

__global__ __launch_bounds__(256) void fill_csr(const int* __restrict__ ei,
                                                int* __restrict__ cursor,
                                                int* __restrict__ slot) {
  int e = blockIdx.x * 256 + threadIdx.x;
  if (e >= EDGES) return;
  int s = ei[e];
  int d = ei[EDGES + e];
  int pos = atomicAdd(&cursor[d], 1);
  slot[pos] = s;
}

// ---------------- aggregation: agg[i] = x[i] + sum_{e: dst==i} x[src[e]] ----
__global__ __launch_bounds__(256) void gather_agg(const float* __restrict__ x,
                                                  const int* __restrict__ off,
                                                  const int* __restrict__ slot,
                                                  float* __restrict__ agg) {
  int node = blockIdx.x * 4 + (threadIdx.x >> 6);
  int lane = threadIdx.x & 63;
  if (node >= NODES) return;
  float2 acc = ((const float2*)(x + (size_t)node * HD))[lane];
  int i = off[node], e1 = off[node + 1];
  for (; i + 1 < e1; i += 2) {
    int sa = slot[i], sb = slot[i + 1];
    float2 va = ((const float2*)(x + (size_t)sa * HD))[lane];
    float2 vb = ((const float2*)(x + (size_t)sb * HD))[lane];
    acc.x += va.x + vb.x;
    acc.y += va.y + vb.y;
  }
  if (i < e1) {
    int sa = slot[i];
    float2 va = ((const float2*)(x + (size_t)sa * HD))[lane];
    acc.x += va.x;
    acc.y += va.y;
  }
  ((float2*)(agg + (size_t)node * HD))[lane] = acc;
}

// ---------------- fused GEMM + BN/ELU epilogue ----------------
// out[M x NC] = epilogue(A[M x 128] @ W[128 x NC] + bias)
// EPI: 1 = BatchNorm+ELU, 2 = ELU, 3 = none
// BM=64 (grid 625), double-buffered LDS with register prefetch.
// NOTE: NODES (40000) is divisible by BM (64) -> no row bounds checks.
template <int NC, int EPI>
__global__ __launch_bounds__(256) void gemm_fused(
    const float* __restrict__ A, const float* __restrict__ W,
    const float* __restrict__ bias, const float* __restrict__ g,
    const float* __restrict__ bt, const float* __restrict__ mu,
    const float* __restrict__ var, float* __restrict__ out) {
  constexpr int BM = 64, BK = 32, TM = 4, TN = NC / 16;
  constexpr int AF4 = BM * BK / (4 * 256);   // float4 A-loads per thread (2)
  constexpr int WF4 = BK * NC / (4 * 256);   // float4 W-loads per thread (4 / 2)
  constexpr int WROW4 = NC / 4;              // float4 per W row
  __shared__ float Ast[2][BK][BM + 4];       // transposed: Ast[buf][k][m]
  __shared__ float Ws[2][BK][NC + 4];

  const int tid = threadIdx.x;
  const int tx = tid & 15;
  const int ty = tid >> 4;
  const int m0 = blockIdx.x * BM;

  // A staging coords: t in [0,512): row r=t>>3 (64 rows), chunk cc=t&7 (8 f4/row)
  const int ar0 = tid >> 3, acc0 = tid & 7;            // it=0
  const int ar1 = (tid + 256) >> 3, acc1 = tid & 7;    // it=1

  // ---- stage tile 0 straight into LDS[0] ----
  {
#pragma unroll
    for (int it = 0; it < AF4; ++it) {
      int r = (tid + it * 256) >> 3, cc = tid & 7;
      float4 v = *(const float4*)(A + (size_t)(m0 + r) * HD + cc * 4);
      Ast[0][cc * 4 + 0][r] = v.x;
      Ast[0][cc * 4 + 1][r] = v.y;
      Ast[0][cc * 4 + 2][r] = v.z;
      Ast[0][cc * 4 + 3][r] = v.w;
    }
#pragma unroll
    for (int it = 0; it < WF4; ++it) {
      int t = tid + it * 256;
      int r = t / WROW4, c4 = t % WROW4;
      *(float4*)&Ws[0][r][c4 * 4] = *(const float4*)(W + (size_t)r * NC + c4 * 4);
    }
  }
  __syncthreads();

  float acc[TM][TN];
#pragma unroll
  for (int i = 0; i < TM; ++i)
#pragma unroll
    for (int j = 0; j < TN; ++j) acc[i][j] = 0.f;

  float4 Av[AF4], Wv[WF4];
  constexpr int KT = HD / BK;  // 4
  for (int kt = 0; kt < KT; ++kt) {
    const int cur = kt & 1, nxt = cur ^ 1;
    if (kt < KT - 1) {
      const int k0 = (kt + 1) * BK;
#pragma unroll
      for (int it = 0; it < AF4; ++it) {
        int r = (tid + it * 256) >> 3, cc = tid & 7;
        Av[it] = *(const float4*)(A + (size_t)(m0 + r) * HD + k0 + cc * 4);
      }
#pragma unroll
      for (int it = 0; it < WF4; ++it) {
        int t = tid + it * 256;
        int r = t / WROW4, c4 = t % WROW4;
        Wv[it] = *(const float4*)(W + (size_t)(k0 + r) * NC + c4 * 4);
      }
    }
#pragma unroll
    for (int k = 0; k < BK; ++k) {
      float a[TM], w[TN];
      *(float4*)&a[0] = *(const float4*)&Ast[cur][k][ty * TM];
#pragma unroll
      for (int j4 = 0; j4 < TN; j4 += 4)
        *(float4*)&w[j4] = *(const float4*)&Ws[cur][k][tx * TN + j4];
#pragma unroll
      for (int i = 0; i < TM; ++i)
#pragma unroll
        for (int j = 0; j < TN; ++j)
          acc[i][j] = fmaf(a[i], w[j], acc[i][j]);
    }
    if (kt < KT - 1) {
#pragma unroll
      for (int it = 0; it < AF4; ++it) {
        int r = (tid + it * 256) >> 3, cc = tid & 7;
        Ast[nxt][cc * 4 + 0][r] = Av[it].x;
        Ast[nxt][cc * 4 + 1][r] = Av[it].y;
        Ast[nxt][cc * 4 + 2][r] = Av[it].z;
        Ast[nxt][cc * 4 + 3][r] = Av[it].w;
      }
#pragma unroll
      for (int it = 0; it < WF4; ++it) {
        int t = tid + it * 256;
        int r = t / WROW4, c4 = t % WROW4;
        *(float4*)&Ws[nxt][r][c4 * 4] = Wv[it];
      }
    }
    __syncthreads();
  }

  // ---- epilogue: per-column constants hoisted ----
  float cb[TN], cs[TN];
#pragma unroll
  for (int j = 0; j < TN; ++j) {
    int c = tx * TN + j;
    if (EPI == 1) {
      float rs = rsqrtf(var[c] + BN_EPS) * g[c];
      cs[j] = rs;
      cb[j] = bt[c] + (bias[c] - mu[c]) * rs;
    } else {
      cs[j] = 1.f;
      cb[j] = bias[c];
    }
  }
#pragma unroll
  for (int i = 0; i < TM; ++i) {
    int m = m0 + ty * TM + i;
#pragma unroll
    for (int j = 0; j < TN; ++j) {
      float t = acc[i][j] * cs[j] + cb[j];
      if (EPI <= 2) t = t > 0.f ? t : expm1f(t);
      acc[i][j] = t;
    }
#pragma unroll
    for (int j4 = 0; j4 < TN; j4 += 4)
      *(float4*)(out + (size_t)m * NC + tx * TN + j4) = *(float4*)&acc[i][j4];
  }
}

extern "C" void kernel_launch(void* const* d_in, const int* in_sizes, int n_in,
                              void* d_out, int out_size, void* d_ws, size_t ws_size,
                              hipStream_t stream) {
  const float* x = (const float*)d_in[0];
  const int* ei  = (const int*)d_in[1];
  const float* p[30];
  for (int i = 0; i < 30 && i < n_in; ++i) p[i] = (const float*)d_in[i];

  float* bufA = (float*)d_ws;
  float* bufB = bufA + (size_t)NODES * HD;
  int* off    = (int*)(bufB + (size_t)NODES * HD);
  int* cursor = off + (NODES + 1);
  int* slot   = cursor + NODES;

  dim3 blk(256);
  const int nodeGrid  = (NODES + 255) / 256;     // 157
  const int edgeGrid  = (EDGES + 255) / 256;     // 2344
  const int gathGrid  = (NODES + 3) / 4;         // 10000
  const int gemmGrid  = NODES / 64;              // 625

  // --- build CSR (by dst) once; reused by all 3 layers ---
  zero_i<<<nodeGrid, blk, 0, stream>>>(cursor, NODES);
  hist_dst<<<edgeGrid, blk, 0, stream>>>(ei, cursor);
  exscan<<<1, 1024, 0, stream>>>(cursor, off);
  copy_i<<<nodeGrid, blk, 0, stream>>>(off, cursor, NODES);
  fill_csr<<<edgeGrid, blk, 0, stream>>>(ei, cursor, slot);

  // --- 3 GIN layers, ping-pong bufA/bufB ---
  const float* cur = x;
  for (int l = 0; l < 3; ++l) {
    const int base = 2 + l * 8;  // c{l}_w1,b1,g,bt,mu,var,w2,b2
    gather_agg<<<gathGrid, blk, 0, stream>>>(cur, off, slot, bufA);
    gemm_fused<128, 1><<<gemmGrid, blk, 0, stream>>>(
        bufA, p[base + 0], p[base + 1], p[base + 2], p[base + 3], p[base + 4],
        p[base + 5], bufB);
    gemm_fused<128, 2><<<gemmGrid, blk, 0, stream>>>(
        bufB, p[base + 6], p[base + 7], nullptr, nullptr, nullptr, nullptr,
        bufA);
    cur = bufA;
    float* t = bufA; bufA = bufB; bufB = t;
  }

  // --- head: lin1 (ELU) then lin2 (plain) -> d_out ---
  gemm_fused<128, 2><<<gemmGrid, blk, 0, stream>>>(
      cur, p[26], p[27], nullptr, nullptr, nullptr, nullptr, bufA);
  gemm_fused<64, 3><<<gemmGrid, blk, 0, stream>>>(
      bufA, p[28], p[29], nullptr, nullptr, nullptr, nullptr, (float*)d_out);
}

// Round 4
// 398.725 us; speedup vs baseline: 1.9594x; 1.9594x over previous
//
#include <hip/hip_runtime.h>
#include <cmath>

#define NODES 40000
#define EDGES 600000
#define HD    128
#define BN_EPS 1e-5f

typedef short bf16x8 __attribute__((ext_vector_type(8)));
typedef float f32x4  __attribute__((ext_vector_type(4)));
typedef unsigned short u16;
typedef unsigned int   u32;

__device__ __forceinline__ float bf2f(u16 u) {
  union { u32 i; float f; } v; v.i = ((u32)u) << 16; return v.f;
}
__device__ __forceinline__ u16 f2bf(float f) {
  union { float f; u32 i; } v; v.f = f;
  u32 r = v.i + 0x7FFF + ((v.i >> 16) & 1);   // RNE
  return (u16)(r >> 16);
}

// ---------------- one-time prep ----------------

__global__ __launch_bounds__(256) void cast_bf16(const float4* __restrict__ s,
                                                 ushort4* __restrict__ d, int n4) {
  int i = blockIdx.x * 256 + threadIdx.x;
  if (i >= n4) return;
  float4 v = s[i];
  ushort4 o;
  o.x = f2bf(v.x); o.y = f2bf(v.y); o.z = f2bf(v.z); o.w = f2bf(v.w);
  d[i] = o;
}

struct WPrep { const float* s[8]; u16* d[8]; };

// transpose+cast: d[n][k] = bf16(s[k][n]); K=128 always, N=128 (m<7) or 64 (m=7)
__global__ __launch_bounds__(256) void prep_weights(WPrep p) {
  int m = blockIdx.y;
  int N = (m == 7) ? 64 : 128;
  int tiles_n = N / 32;
  int tx = blockIdx.x % tiles_n;
  int tk = blockIdx.x / tiles_n;
  if (tk >= 4) return;
  __shared__ float t[32][33];
  int c = threadIdx.x & 31, r8 = threadIdx.x >> 5;
  const float* s = p.s[m];
  for (int rr = 0; rr < 32; rr += 8)
    t[rr + r8][c] = s[(size_t)(tk * 32 + rr + r8) * N + tx * 32 + c];
  __syncthreads();
  u16* d = p.d[m];
  for (int rr = 0; rr < 32; rr += 8)
    d[(size_t)(tx * 32 + rr + r8) * HD + tk * 32 + c] = f2bf(t[c][rr + r8]);
}

// ---------------- CSR build ----------------

__global__ __launch_bounds__(256) void zero_i(int* __restrict__ p, int n) {
  int i = blockIdx.x * 256 + threadIdx.x;
  if (i < n) p[i] = 0;
}

__global__ __launch_bounds__(256) void hist_dst(const int* __restrict__ ei,
                                                int* __restrict__ deg) {
  int e = blockIdx.x * 256 + threadIdx.x;
  if (e < EDGES) atomicAdd(&deg[ei[EDGES + e]], 1);
}

__global__ __launch_bounds__(1024) void exscan(const int* __restrict__ deg,
                                               int* __restrict__ off) {
  __shared__ int wsum[16];
  __shared__ int carry_s;
  const int tid = threadIdx.x;
  const int lane = tid & 63, wv = tid >> 6;
  if (tid == 0) carry_s = 0;
  __syncthreads();
  for (int base = 0; base < NODES; base += 1024) {
    int i = base + tid;
    int v = (i < NODES) ? deg[i] : 0;
    int s = v;
#pragma unroll
    for (int d = 1; d < 64; d <<= 1) {
      int t = __shfl_up(s, d, 64);
      if (lane >= d) s += t;
    }
    if (lane == 63) wsum[wv] = s;
    __syncthreads();
    if (wv == 0) {
      int ws = (lane < 16) ? wsum[lane] : 0;
#pragma unroll
      for (int d = 1; d < 16; d <<= 1) {
        int t = __shfl_up(ws, d, 64);
        if (lane >= d) ws += t;
      }
      if (lane < 16) wsum[lane] = ws;
    }
    __syncthreads();
    int carry = carry_s;
    int excl = carry + (wv > 0 ? wsum[wv - 1] : 0) + s - v;
    if (i < NODES) off[i] = excl;
    __syncthreads();
    if (tid == 1023) carry_s = carry + wsum[15];
    __syncthreads();
  }
  if (tid == 0) off[NODES] = carry_s;
}

__global__ __launch_bounds__(256) void copy_i(const int* __restrict__ a,
                                              int* __restrict__ b, int n) {
  int i = blockIdx.x * 256 + threadIdx.x;
  if (i < n) b[i] = a[i];
}

__global__ __launch_bounds__(256) void fill_csr(const int* __restrict__ ei,
                                                int* __restrict__ cursor,
                                                int* __restrict__ slot) {
  int e = blockIdx.x * 256 + threadIdx.x;
  if (e >= EDGES) return;
  int s = ei[e];
  int d = ei[EDGES + e];
  int pos = atomicAdd(&cursor[d], 1);
  slot[pos] = s;
}

// -------- aggregation (bf16 in/out, fp32 accum): agg[i] = x[i] + sum x[src] --
__global__ __launch_bounds__(256) void gather_agg(const u16* __restrict__ x,
                                                  const int* __restrict__ off,
                                                  const int* __restrict__ slot,
                                                  u16* __restrict__ agg) {
  int node = blockIdx.x * 4 + (threadIdx.x >> 6);
  int lane = threadIdx.x & 63;
  if (node >= NODES) return;
  u32 u = ((const u32*)(x + (size_t)node * HD))[lane];
  float ax = bf2f((u16)u), ay = bf2f((u16)(u >> 16));
  int i = off[node], e1 = off[node + 1];
  for (; i + 3 < e1; i += 4) {
    int s0 = slot[i], s1 = slot[i + 1], s2 = slot[i + 2], s3 = slot[i + 3];
    u32 u0 = ((const u32*)(x + (size_t)s0 * HD))[lane];
    u32 u1 = ((const u32*)(x + (size_t)s1 * HD))[lane];
    u32 u2 = ((const u32*)(x + (size_t)s2 * HD))[lane];
    u32 u3 = ((const u32*)(x + (size_t)s3 * HD))[lane];
    ax += bf2f((u16)u0) + bf2f((u16)u1) + bf2f((u16)u2) + bf2f((u16)u3);
    ay += bf2f((u16)(u0 >> 16)) + bf2f((u16)(u1 >> 16)) +
          bf2f((u16)(u2 >> 16)) + bf2f((u16)(u3 >> 16));
  }
  for (; i < e1; ++i) {
    u32 u0 = ((const u32*)(x + (size_t)slot[i] * HD))[lane];
    ax += bf2f((u16)u0);
    ay += bf2f((u16)(u0 >> 16));
  }
  u32 o = (u32)f2bf(ax) | ((u32)f2bf(ay) << 16);
  ((u32*)(agg + (size_t)node * HD))[lane] = o;
}

// ---------------- MFMA GEMM + BN/ELU epilogue ----------------
// out[M x NC] = epilogue(A[M x 128] @ W[128 x NC] + bias)
// A: bf16 row-major. Wt: bf16 TRANSPOSED [NC][128]. EPI: 1=BN+ELU, 2=ELU, 3=none
// 256 thr = 4 waves; 1 strip of 16 rows per wave; grid = 2500/4 = 625.
template <int NC, int EPI, typename OT>
__global__ __launch_bounds__(256) void gemm_mfma(
    const u16* __restrict__ A, const u16* __restrict__ Wt,
    const float* __restrict__ bias, const float* __restrict__ g,
    const float* __restrict__ bt, const float* __restrict__ mu,
    const float* __restrict__ var, OT* __restrict__ out) {
  constexpr int NT = NC / 16;
  constexpr int PK = HD + 8;          // padded row: 2-way-free LDS bank pattern
  __shared__ u16 Wl[NC][PK];
  __shared__ OT stage[4][16][NC];
  static_assert(NC * sizeof(OT) == 256, "store path assumes 256B rows");

  const int tid = threadIdx.x;
  const int wv = tid >> 6, lane = tid & 63;
  const int col = lane & 15, kg = lane >> 4;

  // stage Wt into LDS (16B per thread-chunk)
  for (int t = tid; t < NC * 16; t += 256) {
    int r = t >> 4, c8 = t & 15;
    *(bf16x8*)&Wl[r][c8 * 8] = *(const bf16x8*)(Wt + (size_t)r * HD + c8 * 8);
  }
  __syncthreads();

  const int strip = blockIdx.x * 4 + wv;
  const u16* Arow = A + (size_t)(strip * 16 + col) * HD;

  f32x4 acc[NT];
#pragma unroll
  for (int t = 0; t < NT; ++t) acc[t] = (f32x4){0.f, 0.f, 0.f, 0.f};

#pragma unroll
  for (int kk = 0; kk < HD; kk += 32) {
    bf16x8 a = *(const bf16x8*)(Arow + kk + kg * 8);
#pragma unroll
    for (int t = 0; t < NT; ++t) {
      bf16x8 b = *(const bf16x8*)&Wl[t * 16 + col][kk + kg * 8];
      acc[t] = __builtin_amdgcn_mfma_f32_16x16x32_bf16(a, b, acc[t], 0, 0, 0);
    }
  }

  // epilogue into per-wave LDS stage (C layout: row = kg*4+r, col = t*16+col)
#pragma unroll
  for (int t = 0; t < NT; ++t) {
    int c = t * 16 + col;
    float sc, bb;
    if (EPI == 1) {
      float rs = rsqrtf(var[c] + BN_EPS) * g[c];
      sc = rs; bb = bt[c] + (bias[c] - mu[c]) * rs;
    } else { sc = 1.f; bb = bias[c]; }
#pragma unroll
    for (int r = 0; r < 4; ++r) {
      float v = acc[t][r] * sc + bb;
      if (EPI <= 2) v = v > 0.f ? v : expm1f(v);
      if constexpr (sizeof(OT) == 2) stage[wv][kg * 4 + r][c] = (OT)f2bf(v);
      else                           stage[wv][kg * 4 + r][c] = v;
    }
  }
  __syncthreads();

  // coalesced 16B store-back: each stage row = 256B = 16 segs
  {
    int r0 = lane >> 4, seg = lane & 15;
#pragma unroll
    for (int rr = 0; rr < 16; rr += 4) {
      int row = rr + r0;
      *(float4*)((char*)(out + (size_t)(strip * 16 + row) * NC) + seg * 16) =
          *(const float4*)((const char*)&stage[wv][row][0] + seg * 16);
    }
  }
}

extern "C" void kernel_launch(void* const* d_in, const int* in_sizes, int n_in,
                              void* d_out, int out_size, void* d_ws, size_t ws_size,
                              hipStream_t stream) {
  const float* x = (const float*)d_in[0];
  const int* ei  = (const int*)d_in[1];
  const float* p[30];
  for (int i = 0; i < 30 && i < n_in; ++i) p[i] = (const float*)d_in[i];

  // workspace layout (bytes): xb | bufA | bufB | Wt[8] | off | cursor | slot
  const size_t FEAT = (size_t)NODES * HD;       // 5.12M elems
  u16* xb   = (u16*)d_ws;
  u16* bufA = xb + FEAT;
  u16* bufB = bufA + FEAT;
  u16* wt   = bufB + FEAT;                      // 7*16384 + 8192 = 122880 u16
  u16* wts[8];
  for (int m = 0; m < 8; ++m) wts[m] = wt + (size_t)m * HD * HD;  // wts[7] uses 64*128
  int* off    = (int*)(wt + 122880);
  int* cursor = off + (NODES + 1);
  int* slot   = cursor + NODES;

  dim3 blk(256);
  const int nodeGrid = (NODES + 255) / 256;
  const int edgeGrid = (EDGES + 255) / 256;
  const int gathGrid = (NODES + 3) / 4;       // 10000
  const int gemmGrid = NODES / 64;            // 625 (2500 strips / 4 waves)

  // prep: cast x, transpose+cast 8 weight matrices
  cast_bf16<<<(int)(FEAT / 4 + 255) / 256, blk, 0, stream>>>(
      (const float4*)x, (ushort4*)xb, (int)(FEAT / 4));
  WPrep wp;
  const int widx[8] = {2, 8, 10, 16, 18, 24, 26, 28};  // c1w1,c1w2,c2w1,c2w2,c3w1,c3w2,lin1,lin2
  for (int m = 0; m < 8; ++m) { wp.s[m] = p[widx[m]]; wp.d[m] = wts[m]; }
  prep_weights<<<dim3(16, 8), blk, 0, stream>>>(wp);

  // CSR (by dst), reused by all 3 layers
  zero_i<<<nodeGrid, blk, 0, stream>>>(cursor, NODES);
  hist_dst<<<edgeGrid, blk, 0, stream>>>(ei, cursor);
  exscan<<<1, 1024, 0, stream>>>(cursor, off);
  copy_i<<<nodeGrid, blk, 0, stream>>>(off, cursor, NODES);
  fill_csr<<<edgeGrid, blk, 0, stream>>>(ei, cursor, slot);

  // 3 GIN layers. Liveness: input dead after gather -> 2 buffers suffice.
  u16* cur = xb;
  u16* t0 = bufA;  // gather target
  u16* t1 = bufB;  // GEMM1 target
  for (int l = 0; l < 3; ++l) {
    const int base = 2 + l * 8;
    gather_agg<<<gathGrid, blk, 0, stream>>>(cur, off, slot, t0);
    gemm_mfma<128, 1, u16><<<gemmGrid, blk, 0, stream>>>(
        t0, wts[l * 2], p[base + 1], p[base + 2], p[base + 3], p[base + 4],
        p[base + 5], t1);
    gemm_mfma<128, 2, u16><<<gemmGrid, blk, 0, stream>>>(
        t1, wts[l * 2 + 1], p[base + 7], nullptr, nullptr, nullptr, nullptr, t0);
    cur = t0;
    u16* tmp = t0; t0 = t1; t1 = tmp;
  }

  // head: lin1 (ELU, bf16 out) then lin2 (plain, fp32 out)
  gemm_mfma<128, 2, u16><<<gemmGrid, blk, 0, stream>>>(
      cur, wts[6], p[27], nullptr, nullptr, nullptr, nullptr, t0);
  gemm_mfma<64, 3, float><<<gemmGrid, blk, 0, stream>>>(
      t0, wts[7], p[29], nullptr, nullptr, nullptr, nullptr, (float*)d_out);
}

// Round 5
// 373.765 us; speedup vs baseline: 2.0902x; 1.0668x over previous
//
#include <hip/hip_runtime.h>
#include <cmath>

#define NODES 40000
#define EDGES 600000
#define HD    128
#define BN_EPS 1e-5f

typedef short bf16x8 __attribute__((ext_vector_type(8)));
typedef float f32x4  __attribute__((ext_vector_type(4)));
typedef unsigned short u16;
typedef unsigned int   u32;

__device__ __forceinline__ float bf2f(u16 u) {
  union { u32 i; float f; } v; v.i = ((u32)u) << 16; return v.f;
}
__device__ __forceinline__ u16 f2bf(float f) {
  union { float f; u32 i; } v; v.f = f;
  u32 r = v.i + 0x7FFF + ((v.i >> 16) & 1);   // RNE
  return (u16)(r >> 16);
}

struct WPrep { const float* s[8]; u16* d[8]; };

// ---------------- fused one-time prep ----------------
// blocks [0,5000): cast x to bf16 | [5000,5128): weight transpose+cast |
// [5128,5285): zero cursor
__global__ __launch_bounds__(256) void prep_all(const float4* __restrict__ x4,
                                                ushort4* __restrict__ xb4,
                                                WPrep p, int* __restrict__ cursor) {
  const int bid = blockIdx.x;
  const int tid = threadIdx.x;
  if (bid < 5000) {
    int i = bid * 256 + tid;           // n4 = 1,280,000 exactly
    float4 v = x4[i];
    ushort4 o;
    o.x = f2bf(v.x); o.y = f2bf(v.y); o.z = f2bf(v.z); o.w = f2bf(v.w);
    xb4[i] = o;
  } else if (bid < 5128) {
    int b = bid - 5000;
    int m = b >> 4, xx = b & 15;
    int N = (m == 7) ? 64 : 128;
    int tiles_n = N / 32;
    int tx = xx % tiles_n, tk = xx / tiles_n;
    if (tk >= 4) return;
    __shared__ float t[32][33];
    int c = tid & 31, r8 = tid >> 5;
    const float* s = p.s[m];
    for (int rr = 0; rr < 32; rr += 8)
      t[rr + r8][c] = s[(size_t)(tk * 32 + rr + r8) * N + tx * 32 + c];
    __syncthreads();
    u16* d = p.d[m];
    for (int rr = 0; rr < 32; rr += 8)
      d[(size_t)(tx * 32 + rr + r8) * HD + tk * 32 + c] = f2bf(t[c][rr + r8]);
  } else {
    int i = (bid - 5128) * 256 + tid;
    if (i < NODES) cursor[i] = 0;
  }
}

// ---------------- CSR build ----------------

__global__ __launch_bounds__(256) void hist_dst(const int* __restrict__ ei,
                                                int* __restrict__ deg) {
  int e = blockIdx.x * 256 + threadIdx.x;
  if (e < EDGES) atomicAdd(&deg[ei[EDGES + e]], 1);
}

// local exclusive scan per 1024-block; 40 blocks cover 40960 >= NODES
__global__ __launch_bounds__(1024) void scan1(const int* __restrict__ deg,
                                              int* __restrict__ off,
                                              int* __restrict__ bsum) {
  __shared__ int wsum[16];
  const int tid = threadIdx.x;
  const int lane = tid & 63, wv = tid >> 6;
  int i = blockIdx.x * 1024 + tid;
  int v = (i < NODES) ? deg[i] : 0;
  int s = v;
#pragma unroll
  for (int d = 1; d < 64; d <<= 1) {
    int t = __shfl_up(s, d, 64);
    if (lane >= d) s += t;
  }
  if (lane == 63) wsum[wv] = s;
  __syncthreads();
  if (wv == 0) {
    int ws = (lane < 16) ? wsum[lane] : 0;
#pragma unroll
    for (int d = 1; d < 16; d <<= 1) {
      int t = __shfl_up(ws, d, 64);
      if (lane >= d) ws += t;
    }
    if (lane < 16) wsum[lane] = ws;
  }
  __syncthreads();
  int base = (wv > 0 ? wsum[wv - 1] : 0);
  if (i < NODES) off[i] = base + s - v;
  if (tid == 1023) bsum[blockIdx.x] = base + s;  // block total
}

// scan 40 block sums -> exclusive prefix (single wave)
__global__ __launch_bounds__(64) void scan2(const int* __restrict__ bsum,
                                            int* __restrict__ bpre) {
  int lane = threadIdx.x;
  int v = (lane < 40) ? bsum[lane] : 0;
  int s = v;
#pragma unroll
  for (int d = 1; d < 64; d <<= 1) {
    int t = __shfl_up(s, d, 64);
    if (lane >= d) s += t;
  }
  if (lane < 40) bpre[lane] = s - v;
}

// add prefix, mirror into cursor; off[NODES] = EDGES (sum of degrees)
__global__ __launch_bounds__(1024) void scan3(int* __restrict__ off,
                                              int* __restrict__ cursor,
                                              const int* __restrict__ bpre) {
  int i = blockIdx.x * 1024 + threadIdx.x;
  if (i < NODES) {
    int o = off[i] + bpre[blockIdx.x];
    off[i] = o;
    cursor[i] = o;
  }
  if (blockIdx.x == 0 && threadIdx.x == 0) off[NODES] = EDGES;
}

__global__ __launch_bounds__(256) void fill_csr(const int* __restrict__ ei,
                                                int* __restrict__ cursor,
                                                int* __restrict__ slot) {
  int e = blockIdx.x * 256 + threadIdx.x;
  if (e >= EDGES) return;
  int s = ei[e];
  int d = ei[EDGES + e];
  int pos = atomicAdd(&cursor[d], 1);
  slot[pos] = s;
}

// -------- aggregation (bf16 in/out, fp32 accum): agg[i] = x[i] + sum x[src] --
// one wave per node, lane = 2 columns; predicated 8-wide edge loop keeps
// 8 row-loads in flight every iteration (no serial-dependent tail).
__global__ __launch_bounds__(256) void gather_agg(const u16* __restrict__ x,
                                                  const int* __restrict__ off,
                                                  const int* __restrict__ slot,
                                                  u16* __restrict__ agg) {
  int node = blockIdx.x * 4 + (threadIdx.x >> 6);
  int lane = threadIdx.x & 63;
  if (node >= NODES) return;
  u32 u = ((const u32*)(x + (size_t)node * HD))[lane];
  float ax = bf2f((u16)u), ay = bf2f((u16)(u >> 16));
  int i = off[node], e1 = off[node + 1];
  for (; i < e1; i += 8) {
    int ss[8];
    u32 uu[8];
#pragma unroll
    for (int j = 0; j < 8; ++j) {
      int idx = i + j;
      ss[j] = slot[idx < e1 ? idx : i];   // clamp: duplicate of a valid slot
    }
#pragma unroll
    for (int j = 0; j < 8; ++j)
      uu[j] = ((const u32*)(x + (size_t)ss[j] * HD))[lane];
#pragma unroll
    for (int j = 0; j < 8; ++j) {
      if (i + j < e1) {
        ax += bf2f((u16)uu[j]);
        ay += bf2f((u16)(uu[j] >> 16));
      }
    }
  }
  u32 o = (u32)f2bf(ax) | ((u32)f2bf(ay) << 16);
  ((u32*)(agg + (size_t)node * HD))[lane] = o;
}

// ---------------- MFMA GEMM + BN/ELU epilogue ----------------
// out[M x NC] = epilogue(A[M x 128] @ W[128 x NC] + bias)
// A: bf16 row-major. Wt: bf16 TRANSPOSED [NC][128]. EPI: 1=BN+ELU, 2=ELU, 3=none
template <int NC, int EPI, typename OT>
__global__ __launch_bounds__(256) void gemm_mfma(
    const u16* __restrict__ A, const u16* __restrict__ Wt,
    const float* __restrict__ bias, const float* __restrict__ g,
    const float* __restrict__ bt, const float* __restrict__ mu,
    const float* __restrict__ var, OT* __restrict__ out) {
  constexpr int NT = NC / 16;
  constexpr int PK = HD + 8;
  __shared__ u16 Wl[NC][PK];
  __shared__ OT stage[4][16][NC];
  static_assert(NC * sizeof(OT) == 256, "store path assumes 256B rows");

  const int tid = threadIdx.x;
  const int wv = tid >> 6, lane = tid & 63;
  const int col = lane & 15, kg = lane >> 4;

  for (int t = tid; t < NC * 16; t += 256) {
    int r = t >> 4, c8 = t & 15;
    *(bf16x8*)&Wl[r][c8 * 8] = *(const bf16x8*)(Wt + (size_t)r * HD + c8 * 8);
  }
  __syncthreads();

  const int strip = blockIdx.x * 4 + wv;
  const u16* Arow = A + (size_t)(strip * 16 + col) * HD;

  f32x4 acc[NT];
#pragma unroll
  for (int t = 0; t < NT; ++t) acc[t] = (f32x4){0.f, 0.f, 0.f, 0.f};

#pragma unroll
  for (int kk = 0; kk < HD; kk += 32) {
    bf16x8 a = *(const bf16x8*)(Arow + kk + kg * 8);
#pragma unroll
    for (int t = 0; t < NT; ++t) {
      bf16x8 b = *(const bf16x8*)&Wl[t * 16 + col][kk + kg * 8];
      acc[t] = __builtin_amdgcn_mfma_f32_16x16x32_bf16(a, b, acc[t], 0, 0, 0);
    }
  }

#pragma unroll
  for (int t = 0; t < NT; ++t) {
    int c = t * 16 + col;
    float sc, bb;
    if (EPI == 1) {
      float rs = rsqrtf(var[c] + BN_EPS) * g[c];
      sc = rs; bb = bt[c] + (bias[c] - mu[c]) * rs;
    } else { sc = 1.f; bb = bias[c]; }
#pragma unroll
    for (int r = 0; r < 4; ++r) {
      float v = acc[t][r] * sc + bb;
      if (EPI <= 2) v = v > 0.f ? v : expm1f(v);
      if constexpr (sizeof(OT) == 2) stage[wv][kg * 4 + r][c] = (OT)f2bf(v);
      else                           stage[wv][kg * 4 + r][c] = v;
    }
  }
  __syncthreads();

  {
    int r0 = lane >> 4, seg = lane & 15;
#pragma unroll
    for (int rr = 0; rr < 16; rr += 4) {
      int row = rr + r0;
      *(float4*)((char*)(out + (size_t)(strip * 16 + row) * NC) + seg * 16) =
          *(const float4*)((const char*)&stage[wv][row][0] + seg * 16);
    }
  }
}

extern "C" void kernel_launch(void* const* d_in, const int* in_sizes, int n_in,
                              void* d_out, int out_size, void* d_ws, size_t ws_size,
                              hipStream_t stream) {
  const float* x = (const float*)d_in[0];
  const int* ei  = (const int*)d_in[1];
  const float* p[30];
  for (int i = 0; i < 30 && i < n_in; ++i) p[i] = (const float*)d_in[i];

  const size_t FEAT = (size_t)NODES * HD;       // 5.12M elems
  u16* xb   = (u16*)d_ws;
  u16* bufA = xb + FEAT;
  u16* bufB = bufA + FEAT;
  u16* wt   = bufB + FEAT;                      // 8 * 128*128 u16 slots
  u16* wts[8];
  for (int m = 0; m < 8; ++m) wts[m] = wt + (size_t)m * HD * HD;
  int* off    = (int*)(wt + 8 * HD * HD);
  int* cursor = off + (NODES + 1);
  int* slot   = cursor + NODES;
  int* bsum   = slot + EDGES;
  int* bpre   = bsum + 64;

  dim3 blk(256);
  const int edgeGrid = (EDGES + 255) / 256;   // 2344
  const int gathGrid = (NODES + 3) / 4;       // 10000
  const int gemmGrid = NODES / 64;            // 625
  const int scanGrid = 40;                    // 40 * 1024 >= NODES

  // prep (cast x, weight transpose+cast, zero cursor) in one dispatch
  WPrep wp;
  const int widx[8] = {2, 8, 10, 16, 18, 24, 26, 28};
  for (int m = 0; m < 8; ++m) { wp.s[m] = p[widx[m]]; wp.d[m] = wts[m]; }
  prep_all<<<5285, blk, 0, stream>>>((const float4*)x, (ushort4*)xb, wp, cursor);

  // CSR (by dst), reused by all 3 layers
  hist_dst<<<edgeGrid, blk, 0, stream>>>(ei, cursor);
  scan1<<<scanGrid, 1024, 0, stream>>>(cursor, off, bsum);
  scan2<<<1, 64, 0, stream>>>(bsum, bpre);
  scan3<<<scanGrid, 1024, 0, stream>>>(off, cursor, bpre);
  fill_csr<<<edgeGrid, blk, 0, stream>>>(ei, cursor, slot);

  // 3 GIN layers
  u16* cur = xb;
  u16* t0 = bufA;
  u16* t1 = bufB;
  for (int l = 0; l < 3; ++l) {
    const int base = 2 + l * 8;
    gather_agg<<<gathGrid, blk, 0, stream>>>(cur, off, slot, t0);
    gemm_mfma<128, 1, u16><<<gemmGrid, blk, 0, stream>>>(
        t0, wts[l * 2], p[base + 1], p[base + 2], p[base + 3], p[base + 4],
        p[base + 5], t1);
    gemm_mfma<128, 2, u16><<<gemmGrid, blk, 0, stream>>>(
        t1, wts[l * 2 + 1], p[base + 7], nullptr, nullptr, nullptr, nullptr, t0);
    cur = t0;
    u16* tmp = t0; t0 = t1; t1 = tmp;
  }

  // head: lin1 (ELU, bf16 out) then lin2 (plain, fp32 out)
  gemm_mfma<128, 2, u16><<<gemmGrid, blk, 0, stream>>>(
      cur, wts[6], p[27], nullptr, nullptr, nullptr, nullptr, t0);
  gemm_mfma<64, 3, float><<<gemmGrid, blk, 0, stream>>>(
      t0, wts[7], p[29], nullptr, nullptr, nullptr, nullptr, (float*)d_out);
}